// Round 2
// baseline (598.507 us; speedup 1.0000x reference)
//
#include <hip/hip_runtime.h>
#include <hip/hip_fp16.h>

// Triplane bilinear sampling, three-phase:
//   Phase 0: spatial counting-sort of points (Morton 5+5+5 bits) so the
//            gather processes spatially-adjacent points together -> corner
//            reads hit L2 instead of random-access Infinity Cache.
//   Phase 1: transpose+downconvert each grid (32,R,R) fp32 -> (R,R,32) fp16
//            in d_ws (all 32 channels of one texel contiguous, 64 B).
//   Phase 2: gather in sorted order; 4 threads per (point,grid), 8 ch each;
//            4x 16 B corner loads, fp32 lerp, 2x float4 store to the ORIGINAL
//            point slot (1152 B contiguous per point -> coalescing survives).
//
// Output layout: out[n][c], c = b*32 + ch, b = level*3 + plane. fp32.

struct GridPtrs { const float* g[9]; };
struct GridOffs { size_t off[9]; };   // element offsets into transposed ws

#define NBUCKETS 32768   // 32^3 Morton cells

// ---------------- Phase 0a: zero histogram ----------------
__global__ __launch_bounds__(256) void zero_counts_kernel(int* __restrict__ counts)
{
    const int i = blockIdx.x * 256 + threadIdx.x;
    if (i < NBUCKETS) counts[i] = 0;
}

__device__ __forceinline__ unsigned expand3(unsigned v)
{
    // 5 bits -> every 3rd bit position
    return (v & 1u) | ((v & 2u) << 2) | ((v & 4u) << 4) |
           ((v & 8u) << 6) | ((v & 16u) << 8);
}

__device__ __forceinline__ unsigned morton_key(float vx, float vy, float vz)
{
    // Map world [-1.6, 1.6] -> cell [0, 31] per axis (values outside clamp).
    const float s = 32.0f / 3.2f;
    int cx = (int)((vx + 1.6f) * s);
    int cy = (int)((vy + 1.6f) * s);
    int cz = (int)((vz + 1.6f) * s);
    cx = min(max(cx, 0), 31);
    cy = min(max(cy, 0), 31);
    cz = min(max(cz, 0), 31);
    return expand3((unsigned)cx) | (expand3((unsigned)cy) << 1) | (expand3((unsigned)cz) << 2);
}

// ---------------- Phase 0b: histogram ----------------
__global__ __launch_bounds__(256) void histogram_kernel(
    const float* __restrict__ pts, int* __restrict__ counts, int n_pts)
{
    const int n = blockIdx.x * 256 + threadIdx.x;
    if (n >= n_pts) return;
    const unsigned k = morton_key(pts[n * 3 + 0], pts[n * 3 + 1], pts[n * 3 + 2]);
    atomicAdd(&counts[k], 1);
}

// ---------------- Phase 0c: exclusive scan (single block) ----------------
// 1024 threads x 32 buckets each. Writes exclusive offsets into cursor.
__global__ __launch_bounds__(1024) void scan_kernel(
    const int* __restrict__ counts, int* __restrict__ cursor)
{
    __shared__ int part[1024];
    const int t = threadIdx.x;
    int local[32];
    int s = 0;
#pragma unroll
    for (int i = 0; i < 32; ++i) {
        local[i] = s;
        s += counts[t * 32 + i];
    }
    part[t] = s;
    __syncthreads();
    // Hillis-Steele inclusive scan over 1024 partials.
    for (int d = 1; d < 1024; d <<= 1) {
        const int v   = part[t];
        const int add = (t >= d) ? part[t - d] : 0;
        __syncthreads();
        part[t] = v + add;
        __syncthreads();
    }
    const int base = (t == 0) ? 0 : part[t - 1];
#pragma unroll
    for (int i = 0; i < 32; ++i) {
        cursor[t * 32 + i] = base + local[i];
    }
}

// ---------------- Phase 0d: scatter permutation ----------------
__global__ __launch_bounds__(256) void scatter_kernel(
    const float* __restrict__ pts, int* __restrict__ cursor,
    int* __restrict__ perm, int n_pts)
{
    const int n = blockIdx.x * 256 + threadIdx.x;
    if (n >= n_pts) return;
    const unsigned k = morton_key(pts[n * 3 + 0], pts[n * 3 + 1], pts[n * 3 + 2]);
    const int pos = atomicAdd(&cursor[k], 1);
    perm[pos] = n;
}

// ---------------- Phase 1: transpose fp32 -> fp16 ----------------
__global__ __launch_bounds__(256) void transpose_grids_h_kernel(
    GridPtrs gp, GridOffs go, __half* __restrict__ t)
{
    const int b = blockIdx.y;
    const int l = b / 3;
    const int R = 128 << l;
    const int T = R * R;

    const int tid  = blockIdx.x * 256 + threadIdx.x;
    const int ch   = tid & 31;
    const int t0   = (tid >> 5) * 16;
    if (t0 >= T) return;

    const float* __restrict__ src = gp.g[b] + (size_t)ch * (size_t)T + t0;
    __half* __restrict__ dst = t + go.off[b];

#pragma unroll
    for (int i = 0; i < 16; ++i) {
        dst[(size_t)(t0 + i) * 32 + ch] = __float2half_rn(src[i]);
    }
}

// ---------------- Phase 2: gather in sorted order ----------------
__device__ __forceinline__ void h8_to_f(const uint4 u, float f[8])
{
    const __half2* h = (const __half2*)&u;
#pragma unroll
    for (int i = 0; i < 4; ++i) {
        const float2 t = __half22float2(h[i]);
        f[2 * i + 0] = t.x;
        f[2 * i + 1] = t.y;
    }
}

__global__ __launch_bounds__(256) void triplane_sample_h_kernel(
    const float* __restrict__ pts,
    const __half* __restrict__ tg,
    GridOffs go,
    const int* __restrict__ perm,
    float* __restrict__ out,
    int n_pts)
{
    const int tid = blockIdx.x * 256 + threadIdx.x;
    const int total = n_pts * 36;           // 9 grids * 4 channel-groups
    if (tid >= total) return;

    const int s  = tid / 36;                // sorted slot
    const int r  = tid - s * 36;            // 0..35
    const int n  = perm[s];                 // original point index
    const int b  = r >> 2;                  // grid index 0..8
    const int ch = (r & 3) << 3;            // channel start: 0,8,16,24
    const int l  = (b >= 6) ? 2 : (b >= 3 ? 1 : 0);
    const int p  = b - l * 3;               // plane 0,1,2

    const float vx = pts[n * 3 + 0];
    const float vy = pts[n * 3 + 1];
    const float vz = pts[n * 3 + 2];

    // Exactly the reference arithmetic: (v - BOUNDS) * (2/(-2*BOUNDS)) - 1
    const float scale = 2.0f / (-2.0f * 1.6f);   // -0.625
    const float px = (vx - 1.6f) * scale - 1.0f;
    const float py = (vy - 1.6f) * scale - 1.0f;
    const float pz = (vz - 1.6f) * scale - 1.0f;

    // plane 0: (y,z)  plane 1: (x,z)  plane 2: (x,y)
    const float cx = (p == 0) ? py : px;
    const float cy = (p == 2) ? py : pz;

    const int   R   = 128 << l;
    const float Rm1 = (float)(R - 1);

    float x = (cx + 1.0f) * 0.5f * Rm1;
    float y = (cy + 1.0f) * 0.5f * Rm1;
    x = fminf(fmaxf(x, 0.0f), Rm1);
    y = fminf(fmaxf(y, 0.0f), Rm1);

    const float x0f = floorf(x);
    const float y0f = floorf(y);
    const float wx  = x - x0f;
    const float wy  = y - y0f;
    const int x0 = (int)x0f;
    const int y0 = (int)y0f;
    const int x1 = min(x0 + 1, R - 1);
    const int y1 = min(y0 + 1, R - 1);

    const __half* base = tg + go.off[b] + ch;
    const size_t s00 = ((size_t)(y0 * R + x0)) * 32;
    const size_t s01 = ((size_t)(y0 * R + x1)) * 32;
    const size_t s10 = ((size_t)(y1 * R + x0)) * 32;
    const size_t s11 = ((size_t)(y1 * R + x1)) * 32;

    const uint4 u00 = *(const uint4*)(base + s00);
    const uint4 u01 = *(const uint4*)(base + s01);
    const uint4 u10 = *(const uint4*)(base + s10);
    const uint4 u11 = *(const uint4*)(base + s11);

    float f00[8], f01[8], f10[8], f11[8];
    h8_to_f(u00, f00);
    h8_to_f(u01, f01);
    h8_to_f(u10, f10);
    h8_to_f(u11, f11);

    const float omwx = 1.0f - wx;
    const float omwy = 1.0f - wy;

    float res[8];
#pragma unroll
    for (int k = 0; k < 8; ++k) {
        res[k] = (f00[k] * omwx + f01[k] * wx) * omwy
               + (f10[k] * omwx + f11[k] * wx) * wy;
    }

    float* op = out + (size_t)n * 288 + b * 32 + ch;
    *(float4*)(op + 0) = make_float4(res[0], res[1], res[2], res[3]);
    *(float4*)(op + 4) = make_float4(res[4], res[5], res[6], res[7]);
}

// ---------------- Fallback: direct gather on channel-major fp32 grids ----------------
__global__ __launch_bounds__(256) void triplane_sample_kernel(
    const float* __restrict__ pts,
    GridPtrs gp,
    float* __restrict__ out,
    int n_pts)
{
    const int tid = blockIdx.x * 256 + threadIdx.x;
    const int total = n_pts * 72;
    if (tid >= total) return;

    const int n  = tid / 72;
    const int c4 = tid - n * 72;
    const int b  = c4 >> 3;
    const int ch = (c4 & 7) << 2;
    const int l  = (b >= 6) ? 2 : (b >= 3 ? 1 : 0);
    const int p  = b - l * 3;

    const float vx = pts[n * 3 + 0];
    const float vy = pts[n * 3 + 1];
    const float vz = pts[n * 3 + 2];

    const float scale = 2.0f / (-2.0f * 1.6f);
    const float px = (vx - 1.6f) * scale - 1.0f;
    const float py = (vy - 1.6f) * scale - 1.0f;
    const float pz = (vz - 1.6f) * scale - 1.0f;

    const float cx = (p == 0) ? py : px;
    const float cy = (p == 2) ? py : pz;

    const int   R   = 128 << l;
    const float Rm1 = (float)(R - 1);

    float x = (cx + 1.0f) * 0.5f * Rm1;
    float y = (cy + 1.0f) * 0.5f * Rm1;
    x = fminf(fmaxf(x, 0.0f), Rm1);
    y = fminf(fmaxf(y, 0.0f), Rm1);

    const float x0f = floorf(x);
    const float y0f = floorf(y);
    const float wx  = x - x0f;
    const float wy  = y - y0f;
    const int x0 = (int)x0f;
    const int y0 = (int)y0f;
    const int x1 = min(x0 + 1, R - 1);
    const int y1 = min(y0 + 1, R - 1);

    const size_t RR   = (size_t)R * (size_t)R;
    const float* base = gp.g[b] + (size_t)ch * RR;

    const int i00 = y0 * R + x0;
    const int i01 = y0 * R + x1;
    const int i10 = y1 * R + x0;
    const int i11 = y1 * R + x1;

    const float omwx = 1.0f - wx;
    const float omwy = 1.0f - wy;

    float rr[4];
#pragma unroll
    for (int k = 0; k < 4; ++k) {
        const float* gk = base + (size_t)k * RR;
        rr[k] = (gk[i00] * omwx + gk[i01] * wx) * omwy
              + (gk[i10] * omwx + gk[i11] * wx) * wy;
    }
    ((float4*)out)[tid] = make_float4(rr[0], rr[1], rr[2], rr[3]);
}

extern "C" void kernel_launch(void* const* d_in, const int* in_sizes, int n_in,
                              void* d_out, int out_size, void* d_ws, size_t ws_size,
                              hipStream_t stream)
{
    const float* pts = (const float*)d_in[0];
    GridPtrs gp;
    for (int i = 0; i < 9; ++i) gp.g[i] = (const float*)d_in[1 + i];
    float* out = (float*)d_out;

    const int n_pts = in_sizes[0] / 3;       // 300000
    const int block = 256;

    // Transposed-grid element offsets and total size (fp16 elements).
    GridOffs go;
    size_t off = 0;
    for (int b = 0; b < 9; ++b) {
        go.off[b] = off;
        const int R = 128 << (b / 3);
        off += (size_t)32 * R * R;
    }

    // Workspace layout (bytes):
    //   [0, tg_bytes)            fp16 transposed grids (~66 MB)
    //   [tg_bytes, +128KB)       counts (32768 ints)
    //   [.., +128KB)             cursor (32768 ints)
    //   [.., +n_pts*4)           perm
    const size_t tg_bytes     = ((off * sizeof(__half)) + 255) & ~(size_t)255;
    const size_t counts_bytes = (size_t)NBUCKETS * 4;
    const size_t needed_bytes = tg_bytes + 2 * counts_bytes + (size_t)n_pts * 4;

    if (ws_size >= needed_bytes) {
        char* wsb   = (char*)d_ws;
        __half* tg  = (__half*)wsb;
        int* counts = (int*)(wsb + tg_bytes);
        int* cursor = (int*)(wsb + tg_bytes + counts_bytes);
        int* perm   = (int*)(wsb + tg_bytes + 2 * counts_bytes);

        // Phase 0: spatial counting-sort of point indices.
        zero_counts_kernel<<<(NBUCKETS + 255) / 256, block, 0, stream>>>(counts);
        histogram_kernel<<<(n_pts + 255) / 256, block, 0, stream>>>(pts, counts, n_pts);
        scan_kernel<<<1, 1024, 0, stream>>>(counts, cursor);
        scatter_kernel<<<(n_pts + 255) / 256, block, 0, stream>>>(pts, cursor, perm, n_pts);

        // Phase 1: transpose+convert. Largest grid (R=512): T=262144 texels,
        // threads = 32 * T/16 = 524288 -> 2048 blocks of 256.
        dim3 tgrid(2048, 9, 1);
        transpose_grids_h_kernel<<<tgrid, block, 0, stream>>>(gp, go, tg);

        // Phase 2: gather in Morton order. 4 threads/(point,grid).
        const int total = n_pts * 36;
        const int grid  = (total + block - 1) / block;
        triplane_sample_h_kernel<<<grid, block, 0, stream>>>(pts, tg, go, perm, out, n_pts);
    } else {
        const int total = n_pts * 72;
        const int grid  = (total + block - 1) / block;
        triplane_sample_kernel<<<grid, block, 0, stream>>>(pts, gp, out, n_pts);
    }
}

// Round 3
// 551.420 us; speedup vs baseline: 1.0854x; 1.0854x over previous
//
#include <hip/hip_runtime.h>
#include <hip/hip_fp16.h>

// Triplane bilinear sampling, two-phase with fp16 transposed grids:
//   Phase 1: LDS-tiled transpose+downconvert (32,R,R) fp32 -> (R,R,32) fp16.
//            Vector float4 reads (each lane consumes full lines from
//            registers, no L1-thrash), coalesced 16-B vector writes.
//   Phase 2: gather. 4 threads per (point,grid); each owns 8 channels:
//            4x 16 B corner loads (8 halves), fp32 lerp, 2x 16 B NONTEMPORAL
//            stores (output stream must not evict the fp16 grids from L3).
//
// Round-2 lesson: Morton-sorting the points cost ~35 us of pre-pass and won
// zero in the gather -> gather is not read-locality bound; sort reverted.
//
// Output layout: out[n][c], c = b*32 + ch, b = level*3 + plane. fp32.

typedef float        f32x4 __attribute__((ext_vector_type(4)));
typedef unsigned int u32x4 __attribute__((ext_vector_type(4)));

struct GridPtrs { const float* g[9]; };
struct GridOffs { size_t off[9]; };   // element offsets into transposed ws

#define TP_TEX 64   // texels per transpose tile (one block)

// ---------------- Phase 1: LDS-tiled transpose fp32 -> fp16 ----------------
// gridDim.y = b (0..8); gridDim.x covers T/64 tiles of the largest grid,
// smaller grids early-out.
// Stage-in : thread t: ch = t>>3, part = (t&7)*8 -> two float4 loads of one
//            channel row segment (nontemporal: stream-once data), convert,
//            scatter into lds[tex][ch] (row stride 33 halves).
// Stage-out: thread t: tex = t>>2, q = (t&3)*8 -> pack 8 halves, one 16-B
//            coalesced global write (cached: the gather will read it).
__global__ __launch_bounds__(256) void transpose_grids_h_kernel(
    GridPtrs gp, GridOffs go, __half* __restrict__ t)
{
    const int b = blockIdx.y;
    const int l = b / 3;
    const int R = 128 << l;
    const int T = R * R;

    const int tile0 = blockIdx.x * TP_TEX;
    if (tile0 >= T) return;

    __shared__ unsigned short lds[TP_TEX * 33];

    const int tid = threadIdx.x;

    // stage-in
    {
        const int ch   = tid >> 3;          // 0..31
        const int part = (tid & 7) << 3;    // 0..56
        const float* __restrict__ src = gp.g[b] + (size_t)ch * (size_t)T + tile0 + part;
        const f32x4 a0 = __builtin_nontemporal_load((const f32x4*)src);
        const f32x4 a1 = __builtin_nontemporal_load((const f32x4*)(src + 4));
#pragma unroll
        for (int k = 0; k < 4; ++k)
            lds[(part + k) * 33 + ch] = __half_as_ushort(__float2half_rn(a0[k]));
#pragma unroll
        for (int k = 0; k < 4; ++k)
            lds[(part + 4 + k) * 33 + ch] = __half_as_ushort(__float2half_rn(a1[k]));
    }
    __syncthreads();

    // stage-out
    {
        const int tex = tid >> 2;           // 0..63
        const int q   = (tid & 3) << 3;     // 0,8,16,24
        const unsigned short* row = &lds[tex * 33 + q];
        u32x4 v;
#pragma unroll
        for (int k = 0; k < 4; ++k) {
            const unsigned lo = row[2 * k];
            const unsigned hi = row[2 * k + 1];
            v[k] = lo | (hi << 16);
        }
        __half* dst = t + go.off[b] + (size_t)(tile0 + tex) * 32 + q;
        *(u32x4*)dst = v;
    }
}

// ---------------- Phase 2: gather (fp16 transposed grids) ----------------
__device__ __forceinline__ void h8_to_f(const uint4 u, float f[8])
{
    const __half2* h = (const __half2*)&u;
#pragma unroll
    for (int i = 0; i < 4; ++i) {
        const float2 t = __half22float2(h[i]);
        f[2 * i + 0] = t.x;
        f[2 * i + 1] = t.y;
    }
}

__global__ __launch_bounds__(256) void triplane_sample_h_kernel(
    const float* __restrict__ pts,
    const __half* __restrict__ tg,
    GridOffs go,
    float* __restrict__ out,
    int n_pts)
{
    const int tid = blockIdx.x * 256 + threadIdx.x;
    const int total = n_pts * 36;           // 9 grids * 4 channel-groups
    if (tid >= total) return;

    const int n  = tid / 36;
    const int r  = tid - n * 36;            // 0..35
    const int b  = r >> 2;                  // grid index 0..8
    const int ch = (r & 3) << 3;            // channel start: 0,8,16,24
    const int l  = (b >= 6) ? 2 : (b >= 3 ? 1 : 0);
    const int p  = b - l * 3;               // plane 0,1,2

    const float vx = pts[n * 3 + 0];
    const float vy = pts[n * 3 + 1];
    const float vz = pts[n * 3 + 2];

    // Exactly the reference arithmetic: (v - BOUNDS) * (2/(-2*BOUNDS)) - 1
    const float scale = 2.0f / (-2.0f * 1.6f);   // -0.625
    const float px = (vx - 1.6f) * scale - 1.0f;
    const float py = (vy - 1.6f) * scale - 1.0f;
    const float pz = (vz - 1.6f) * scale - 1.0f;

    // plane 0: (y,z)  plane 1: (x,z)  plane 2: (x,y)
    const float cx = (p == 0) ? py : px;
    const float cy = (p == 2) ? py : pz;

    const int   R   = 128 << l;
    const float Rm1 = (float)(R - 1);

    float x = (cx + 1.0f) * 0.5f * Rm1;
    float y = (cy + 1.0f) * 0.5f * Rm1;
    x = fminf(fmaxf(x, 0.0f), Rm1);
    y = fminf(fmaxf(y, 0.0f), Rm1);

    const float x0f = floorf(x);
    const float y0f = floorf(y);
    const float wx  = x - x0f;
    const float wy  = y - y0f;
    const int x0 = (int)x0f;
    const int y0 = (int)y0f;
    const int x1 = min(x0 + 1, R - 1);
    const int y1 = min(y0 + 1, R - 1);

    const __half* base = tg + go.off[b] + ch;
    const size_t s00 = ((size_t)(y0 * R + x0)) * 32;
    const size_t s01 = ((size_t)(y0 * R + x1)) * 32;
    const size_t s10 = ((size_t)(y1 * R + x0)) * 32;
    const size_t s11 = ((size_t)(y1 * R + x1)) * 32;

    const uint4 u00 = *(const uint4*)(base + s00);
    const uint4 u01 = *(const uint4*)(base + s01);
    const uint4 u10 = *(const uint4*)(base + s10);
    const uint4 u11 = *(const uint4*)(base + s11);

    float f00[8], f01[8], f10[8], f11[8];
    h8_to_f(u00, f00);
    h8_to_f(u01, f01);
    h8_to_f(u10, f10);
    h8_to_f(u11, f11);

    const float omwx = 1.0f - wx;
    const float omwy = 1.0f - wy;

    float res[8];
#pragma unroll
    for (int k = 0; k < 8; ++k) {
        res[k] = (f00[k] * omwx + f01[k] * wx) * omwy
               + (f10[k] * omwx + f11[k] * wx) * wy;
    }

    // Nontemporal: the 346 MB output stream must not evict the 63 MB fp16
    // grids from L3 while the gather is still reading them.
    float* op = out + (size_t)n * 288 + b * 32 + ch;
    const f32x4 r0 = {res[0], res[1], res[2], res[3]};
    const f32x4 r1 = {res[4], res[5], res[6], res[7]};
    __builtin_nontemporal_store(r0, (f32x4*)op);
    __builtin_nontemporal_store(r1, (f32x4*)(op + 4));
}

// ---------------- Fallback: direct gather on channel-major fp32 grids ----------------
__global__ __launch_bounds__(256) void triplane_sample_kernel(
    const float* __restrict__ pts,
    GridPtrs gp,
    float* __restrict__ out,
    int n_pts)
{
    const int tid = blockIdx.x * 256 + threadIdx.x;
    const int total = n_pts * 72;
    if (tid >= total) return;

    const int n  = tid / 72;
    const int c4 = tid - n * 72;
    const int b  = c4 >> 3;
    const int ch = (c4 & 7) << 2;
    const int l  = (b >= 6) ? 2 : (b >= 3 ? 1 : 0);
    const int p  = b - l * 3;

    const float vx = pts[n * 3 + 0];
    const float vy = pts[n * 3 + 1];
    const float vz = pts[n * 3 + 2];

    const float scale = 2.0f / (-2.0f * 1.6f);
    const float px = (vx - 1.6f) * scale - 1.0f;
    const float py = (vy - 1.6f) * scale - 1.0f;
    const float pz = (vz - 1.6f) * scale - 1.0f;

    const float cx = (p == 0) ? py : px;
    const float cy = (p == 2) ? py : pz;

    const int   R   = 128 << l;
    const float Rm1 = (float)(R - 1);

    float x = (cx + 1.0f) * 0.5f * Rm1;
    float y = (cy + 1.0f) * 0.5f * Rm1;
    x = fminf(fmaxf(x, 0.0f), Rm1);
    y = fminf(fmaxf(y, 0.0f), Rm1);

    const float x0f = floorf(x);
    const float y0f = floorf(y);
    const float wx  = x - x0f;
    const float wy  = y - y0f;
    const int x0 = (int)x0f;
    const int y0 = (int)y0f;
    const int x1 = min(x0 + 1, R - 1);
    const int y1 = min(y0 + 1, R - 1);

    const size_t RR   = (size_t)R * (size_t)R;
    const float* base = gp.g[b] + (size_t)ch * RR;

    const int i00 = y0 * R + x0;
    const int i01 = y0 * R + x1;
    const int i10 = y1 * R + x0;
    const int i11 = y1 * R + x1;

    const float omwx = 1.0f - wx;
    const float omwy = 1.0f - wy;

    float rr[4];
#pragma unroll
    for (int k = 0; k < 4; ++k) {
        const float* gk = base + (size_t)k * RR;
        rr[k] = (gk[i00] * omwx + gk[i01] * wx) * omwy
              + (gk[i10] * omwx + gk[i11] * wx) * wy;
    }
    ((float4*)out)[tid] = make_float4(rr[0], rr[1], rr[2], rr[3]);
}

extern "C" void kernel_launch(void* const* d_in, const int* in_sizes, int n_in,
                              void* d_out, int out_size, void* d_ws, size_t ws_size,
                              hipStream_t stream)
{
    const float* pts = (const float*)d_in[0];
    GridPtrs gp;
    for (int i = 0; i < 9; ++i) gp.g[i] = (const float*)d_in[1 + i];
    float* out = (float*)d_out;

    const int n_pts = in_sizes[0] / 3;       // 300000
    const int block = 256;

    // Transposed-grid element offsets and total size (fp16 elements).
    GridOffs go;
    size_t off = 0;
    for (int b = 0; b < 9; ++b) {
        go.off[b] = off;
        const int R = 128 << (b / 3);
        off += (size_t)32 * R * R;
    }
    const size_t needed_bytes = off * sizeof(__half);   // ~66 MB

    if (ws_size >= needed_bytes) {
        __half* tg = (__half*)d_ws;
        // Phase 1: LDS-tiled transpose+convert. Largest grid: T=262144,
        // tiles = T/64 = 4096; smaller grids early-out on blockIdx.x.
        dim3 tgrid(4096, 9, 1);
        transpose_grids_h_kernel<<<tgrid, block, 0, stream>>>(gp, go, tg);
        // Phase 2: gather. 4 threads/(point,grid).
        const int total = n_pts * 36;
        const int grid  = (total + block - 1) / block;
        triplane_sample_h_kernel<<<grid, block, 0, stream>>>(pts, tg, go, out, n_pts);
    } else {
        const int total = n_pts * 72;
        const int grid  = (total + block - 1) / block;
        triplane_sample_kernel<<<grid, block, 0, stream>>>(pts, gp, out, n_pts);
    }
}

// Round 4
// 539.381 us; speedup vs baseline: 1.1096x; 1.0223x over previous
//
#include <hip/hip_runtime.h>
#include <hip/hip_fp16.h>

// Triplane bilinear sampling, two-phase with DUAL fp16 transposed grids:
//   Phase 1: LDS-tiled transpose+downconvert (32,R,R) fp32 -> (R,R,32) fp16,
//            written TWICE: copy A (natural) and copy B (x-shifted by one
//            texel: B[y][x] = A[y][x+1], B[y][R-1] = A[y][R-1]).
//   Phase 2: gather. 4 threads per (point,grid); each owns 8 channels.
//            Copy chosen by parity of x0 so the (x0,x1) 64B-block pair ALWAYS
//            sits in one fully-used 128-B cache line -> 2 lines per
//            (point,grid) instead of avg 3 (-33% L2/L3 line traffic).
//            fp32 lerp, 2x 16 B nontemporal stores.
//
// Lessons so far: Morton sort (locality) = null; fp16 (bytes) = win;
//   => gather is order-invariant line-traffic bound. This round attacks
//   line utilization directly. Output bits identical to round 3.
//
// Output layout: out[n][c], c = b*32 + ch, b = level*3 + plane. fp32.

typedef float        f32x4 __attribute__((ext_vector_type(4)));
typedef unsigned int u32x4 __attribute__((ext_vector_type(4)));

struct GridPtrs { const float* g[9]; };
struct GridOffs { size_t off[9]; };   // half-element offsets of copy A grids

#define TP_TEX 64                      // texels per transpose tile (one block)
#define TOTAL_HALVES 33030144ull       // 3*(2^19 + 2^21 + 2^23); copy B base

// ---------------- Phase 1: LDS-tiled transpose fp32 -> fp16 (A + B) -------
// gridDim.y = b (0..8); gridDim.x covers T/64 tiles of the largest grid,
// smaller grids early-out. Tiles are 64 texels and never cross a row
// (R % 64 == 0), so the x-shift logic is per-thread local.
__global__ __launch_bounds__(256) void transpose_grids_h_kernel(
    GridPtrs gp, GridOffs go, __half* __restrict__ t)
{
    const int b = blockIdx.y;
    const int l = b / 3;
    const int R = 128 << l;
    const int T = R * R;

    const int tile0 = blockIdx.x * TP_TEX;
    if (tile0 >= T) return;

    __shared__ unsigned short lds[TP_TEX * 33];

    const int tid = threadIdx.x;

    // stage-in: thread t: ch = t>>3, part = (t&7)*8 -> two float4 loads,
    // convert, scatter into lds[tex][ch] (row stride 33 halves).
    {
        const int ch   = tid >> 3;          // 0..31
        const int part = (tid & 7) << 3;    // 0..56
        const float* __restrict__ src = gp.g[b] + (size_t)ch * (size_t)T + tile0 + part;
        const f32x4 a0 = __builtin_nontemporal_load((const f32x4*)src);
        const f32x4 a1 = __builtin_nontemporal_load((const f32x4*)(src + 4));
#pragma unroll
        for (int k = 0; k < 4; ++k)
            lds[(part + k) * 33 + ch] = __half_as_ushort(__float2half_rn(a0[k]));
#pragma unroll
        for (int k = 0; k < 4; ++k)
            lds[(part + 4 + k) * 33 + ch] = __half_as_ushort(__float2half_rn(a1[k]));
    }
    __syncthreads();

    // stage-out: thread t: tex = t>>2, q = (t&3)*8 -> pack 8 halves,
    // write copy A at texel g, copy B at texel g-1 (x>=1), plus the
    // row-edge duplicate B[g] when x == R-1.
    {
        const int tex = tid >> 2;           // 0..63
        const int q   = (tid & 3) << 3;     // 0,8,16,24
        const unsigned short* row = &lds[tex * 33 + q];
        u32x4 v;
#pragma unroll
        for (int k = 0; k < 4; ++k) {
            const unsigned lo = row[2 * k];
            const unsigned hi = row[2 * k + 1];
            v[k] = lo | (hi << 16);
        }
        const int g = tile0 + tex;
        const int x = g & (R - 1);          // R is a power of two

        __half* A = t + go.off[b];
        __half* B = t + TOTAL_HALVES + go.off[b];

        *(u32x4*)(A + (size_t)g * 32 + q) = v;
        if (x >= 1)     *(u32x4*)(B + (size_t)(g - 1) * 32 + q) = v;
        if (x == R - 1) *(u32x4*)(B + (size_t)g       * 32 + q) = v;
    }
}

// ---------------- Phase 2: gather (dual fp16 transposed grids) ------------
__device__ __forceinline__ void h8_to_f(const uint4 u, float f[8])
{
    const __half2* h = (const __half2*)&u;
#pragma unroll
    for (int i = 0; i < 4; ++i) {
        const float2 t = __half22float2(h[i]);
        f[2 * i + 0] = t.x;
        f[2 * i + 1] = t.y;
    }
}

__global__ __launch_bounds__(256) void triplane_sample_h_kernel(
    const float* __restrict__ pts,
    const __half* __restrict__ tg,
    float* __restrict__ out,
    int n_pts)
{
    const int tid = blockIdx.x * 256 + threadIdx.x;
    const int total = n_pts * 36;           // 9 grids * 4 channel-groups
    if (tid >= total) return;

    const int n  = tid / 36;
    const int r  = tid - n * 36;            // 0..35
    const int b  = r >> 2;                  // grid index 0..8
    const int ch = (r & 3) << 3;            // channel start: 0,8,16,24
    const int l  = (b >= 6) ? 2 : (b >= 3 ? 1 : 0);
    const int p  = b - l * 3;               // plane 0,1,2

    const float vx = pts[n * 3 + 0];
    const float vy = pts[n * 3 + 1];
    const float vz = pts[n * 3 + 2];

    // Exactly the reference arithmetic: (v - BOUNDS) * (2/(-2*BOUNDS)) - 1
    const float scale = 2.0f / (-2.0f * 1.6f);   // -0.625
    const float px = (vx - 1.6f) * scale - 1.0f;
    const float py = (vy - 1.6f) * scale - 1.0f;
    const float pz = (vz - 1.6f) * scale - 1.0f;

    // plane 0: (y,z)  plane 1: (x,z)  plane 2: (x,y)
    const float cx = (p == 0) ? py : px;
    const float cy = (p == 2) ? py : pz;

    const int   R   = 128 << l;
    const float Rm1 = (float)(R - 1);

    float x = (cx + 1.0f) * 0.5f * Rm1;
    float y = (cy + 1.0f) * 0.5f * Rm1;
    x = fminf(fmaxf(x, 0.0f), Rm1);
    y = fminf(fmaxf(y, 0.0f), Rm1);

    const float x0f = floorf(x);
    const float y0f = floorf(y);
    const float wx  = x - x0f;
    const float wy  = y - y0f;
    const int x0 = (int)x0f;
    const int y0 = (int)y0f;
    const int y1 = min(y0 + 1, R - 1);

    // Parity-aligned pair read: copy A when x0 even, x-shifted copy B when
    // x0 odd. Either way v00 = block xb, v01 = block xb+1 (same 128-B line),
    // with the x1 = min(x0+1, R-1) clamp baked into copy B's edge column.
    const int par = x0 & 1;
    const int xb  = x0 - par;               // even

    // off(b) = base(l) + p * (524288 << 2l)   [half elements]
    const size_t lbase = (l == 0) ? 0ull : ((l == 1) ? 1572864ull : 7864320ull);
    const size_t off_b = lbase + ((size_t)p << (19 + 2 * l));

    const __half* gbase = tg + (par ? TOTAL_HALVES : 0ull) + off_b + ch;
    const size_t r0 = ((size_t)(y0 * R + xb)) * 32;
    const size_t r1 = ((size_t)(y1 * R + xb)) * 32;

    const uint4 u00 = *(const uint4*)(gbase + r0);
    const uint4 u01 = *(const uint4*)(gbase + r0 + 32);
    const uint4 u10 = *(const uint4*)(gbase + r1);
    const uint4 u11 = *(const uint4*)(gbase + r1 + 32);

    float f00[8], f01[8], f10[8], f11[8];
    h8_to_f(u00, f00);
    h8_to_f(u01, f01);
    h8_to_f(u10, f10);
    h8_to_f(u11, f11);

    const float omwx = 1.0f - wx;
    const float omwy = 1.0f - wy;

    float res[8];
#pragma unroll
    for (int k = 0; k < 8; ++k) {
        res[k] = (f00[k] * omwx + f01[k] * wx) * omwy
               + (f10[k] * omwx + f11[k] * wx) * wy;
    }

    // Nontemporal: the 346 MB output stream must not evict the grids from L3.
    float* op = out + (size_t)n * 288 + b * 32 + ch;
    const f32x4 r0v = {res[0], res[1], res[2], res[3]};
    const f32x4 r1v = {res[4], res[5], res[6], res[7]};
    __builtin_nontemporal_store(r0v, (f32x4*)op);
    __builtin_nontemporal_store(r1v, (f32x4*)(op + 4));
}

// ---------------- Fallback: direct gather on channel-major fp32 grids -----
__global__ __launch_bounds__(256) void triplane_sample_kernel(
    const float* __restrict__ pts,
    GridPtrs gp,
    float* __restrict__ out,
    int n_pts)
{
    const int tid = blockIdx.x * 256 + threadIdx.x;
    const int total = n_pts * 72;
    if (tid >= total) return;

    const int n  = tid / 72;
    const int c4 = tid - n * 72;
    const int b  = c4 >> 3;
    const int ch = (c4 & 7) << 2;
    const int l  = (b >= 6) ? 2 : (b >= 3 ? 1 : 0);
    const int p  = b - l * 3;

    const float vx = pts[n * 3 + 0];
    const float vy = pts[n * 3 + 1];
    const float vz = pts[n * 3 + 2];

    const float scale = 2.0f / (-2.0f * 1.6f);
    const float px = (vx - 1.6f) * scale - 1.0f;
    const float py = (vy - 1.6f) * scale - 1.0f;
    const float pz = (vz - 1.6f) * scale - 1.0f;

    const float cx = (p == 0) ? py : px;
    const float cy = (p == 2) ? py : pz;

    const int   R   = 128 << l;
    const float Rm1 = (float)(R - 1);

    float x = (cx + 1.0f) * 0.5f * Rm1;
    float y = (cy + 1.0f) * 0.5f * Rm1;
    x = fminf(fmaxf(x, 0.0f), Rm1);
    y = fminf(fmaxf(y, 0.0f), Rm1);

    const float x0f = floorf(x);
    const float y0f = floorf(y);
    const float wx  = x - x0f;
    const float wy  = y - y0f;
    const int x0 = (int)x0f;
    const int y0 = (int)y0f;
    const int x1 = min(x0 + 1, R - 1);
    const int y1 = min(y0 + 1, R - 1);

    const size_t RR   = (size_t)R * (size_t)R;
    const float* base = gp.g[b] + (size_t)ch * RR;

    const int i00 = y0 * R + x0;
    const int i01 = y0 * R + x1;
    const int i10 = y1 * R + x0;
    const int i11 = y1 * R + x1;

    const float omwx = 1.0f - wx;
    const float omwy = 1.0f - wy;

    float rr[4];
#pragma unroll
    for (int k = 0; k < 4; ++k) {
        const float* gk = base + (size_t)k * RR;
        rr[k] = (gk[i00] * omwx + gk[i01] * wx) * omwy
              + (gk[i10] * omwx + gk[i11] * wx) * wy;
    }
    ((float4*)out)[tid] = make_float4(rr[0], rr[1], rr[2], rr[3]);
}

extern "C" void kernel_launch(void* const* d_in, const int* in_sizes, int n_in,
                              void* d_out, int out_size, void* d_ws, size_t ws_size,
                              hipStream_t stream)
{
    const float* pts = (const float*)d_in[0];
    GridPtrs gp;
    for (int i = 0; i < 9; ++i) gp.g[i] = (const float*)d_in[1 + i];
    float* out = (float*)d_out;

    const int n_pts = in_sizes[0] / 3;       // 300000
    const int block = 256;

    // Copy-A half-element offsets; copy B lives at +TOTAL_HALVES.
    GridOffs go;
    size_t off = 0;
    for (int b = 0; b < 9; ++b) {
        go.off[b] = off;
        const int R = 128 << (b / 3);
        off += (size_t)32 * R * R;
    }
    const size_t needed_bytes = 2 * off * sizeof(__half);   // ~132 MB (A + B)

    if (ws_size >= needed_bytes) {
        __half* tg = (__half*)d_ws;
        // Phase 1: LDS-tiled transpose+convert, dual-copy write.
        dim3 tgrid(4096, 9, 1);
        transpose_grids_h_kernel<<<tgrid, block, 0, stream>>>(gp, go, tg);
        // Phase 2: gather. 4 threads/(point,grid).
        const int total = n_pts * 36;
        const int grid  = (total + block - 1) / block;
        triplane_sample_h_kernel<<<grid, block, 0, stream>>>(pts, tg, out, n_pts);
    } else {
        const int total = n_pts * 72;
        const int grid  = (total + block - 1) / block;
        triplane_sample_kernel<<<grid, block, 0, stream>>>(pts, gp, out, n_pts);
    }
}